// Round 9
// baseline (171.751 us; speedup 1.0000x reference)
//
#include <hip/hip_runtime.h>
#include <hip/hip_bf16.h>
#include <math.h>

// CommNetWork fused MFMA kernel v3, MI355X gfx950. fp32 in / fp32 out.
// R8 post-mortem: ~76us of wall time was the prep dispatch + dependency edge;
// main kernel latency-bound at 2 waves/SIMD. v3: SINGLE kernel (fp32 weights
// converted in-register), 1024 threads = 16 waves = 4 waves/SIMD, GRU split
// into r/z-pass + n-pass to stay under the hard 128-VGPR cap (r parked in
// dead T0 as bf16, z in 4 f32x4 regs), fast v_exp-based sigmoid/tanh.

typedef __bf16  bf16x8 __attribute__((ext_vector_type(8)));
typedef float   f32x4  __attribute__((ext_vector_type(4)));

#define DIN 128
#define H0  256
#define LOG2E 1.44269504088896f

__device__ __forceinline__ f32x4 mfma16(bf16x8 a, bf16x8 b, f32x4 c) {
    return __builtin_amdgcn_mfma_f32_16x16x32_bf16(a, b, c, 0, 0, 0);
}
__device__ __forceinline__ float bf2f(__hip_bfloat16 x) { return __bfloat162float(x); }
__device__ __forceinline__ __hip_bfloat16 f2bf(float x) { return __float2bfloat16(x); }

// v_exp_f32-based activations (1-ulp class; saturate correctly at +-inf)
__device__ __forceinline__ float fsigmoid(float x) {
    float e = __builtin_amdgcn_exp2f(-LOG2E * x);
    return __builtin_amdgcn_rcpf(1.0f + e);
}
__device__ __forceinline__ float ftanh(float x) {
    float e = __builtin_amdgcn_exp2f(2.0f * LOG2E * x);
    return 1.0f - 2.0f * __builtin_amdgcn_rcpf(1.0f + e);
}

// fp32 weight fragment -> bf16x8 (idx multiple of 8)
__device__ __forceinline__ bf16x8 w8f(const float* __restrict__ p, int idx) {
    f32x4 a = *(const f32x4*)(p + idx);
    f32x4 b = *(const f32x4*)(p + idx + 4);
    bf16x8 r;
    #pragma unroll
    for (int j = 0; j < 4; j++) { r[j] = (__bf16)a[j]; r[j + 4] = (__bf16)b[j]; }
    return r;
}

// element (r,k) of a swizzled 64x256 bf16 tile (32 chunks of 8 per row)
__device__ __forceinline__ int tadr(int r, int k) {
    return (r << 8) + ((((k >> 3) ^ r) & 31) << 3) + (k & 7);
}
// element (r,k) of the swizzled 64x128 obs tile (16 chunks of 8 per row)
__device__ __forceinline__ int oadr(int r, int k) {
    return (r << 7) + ((((k >> 3) ^ r) & 15) << 3) + (k & 7);
}

__global__ __launch_bounds__(1024, 1) void commnet_mfma(
    const float* __restrict__ obs,
    const float* __restrict__ W_enc, const float* __restrict__ b_enc,
    const float* __restrict__ W_obs, const float* __restrict__ b_obs,
    const float* __restrict__ W_ih,  const float* __restrict__ b_ih,
    const float* __restrict__ W_hh,  const float* __restrict__ b_hh,
    const float* __restrict__ W_val, const float* __restrict__ b_val,
    const float* __restrict__ W_dec, const float* __restrict__ b_dec,
    float* __restrict__ out)
{
    __shared__ __align__(16) __hip_bfloat16 T0[64 * 256];  // X1 -> r -> h'
    __shared__ __align__(16) __hip_bfloat16 T1[64 * 256];  // obs -> H -> V

    const int tid  = threadIdx.x;
    const int wave = tid >> 6;           // 0..15
    const int lane = tid & 63;
    const int quad = lane >> 4;
    const int lc   = lane & 15;          // tile col (n) / A-frag row (m)
    const int row0 = blockIdx.x * 64;    // global row base for this batch
    const int ko16 = quad * 8;           // k offset of this lane's fragment
    const int n    = wave * 16 + lc;     // this wave's column (256-wide stages)

    // ---- stage obs (fp32 global) -> bf16 swizzled T1: 1 chunk/thread ----
    {
        const int r = tid >> 4;
        const int c = (tid & 15) << 3;
        const float* src = obs + (row0 + r) * DIN + c;
        f32x4 a = *(const f32x4*)src;
        f32x4 b = *(const f32x4*)(src + 4);
        bf16x8 v;
        #pragma unroll
        for (int j = 0; j < 4; j++) { v[j] = (__bf16)a[j]; v[j + 4] = (__bf16)b[j]; }
        *(bf16x8*)&T1[oadr(r, c)] = v;
    }
    __syncthreads();

    // ---- stage 1: X1 = relu(obs @ W_enc^T + b_enc) -> T0 ----
    {
        const float bias = b_enc[n];
        f32x4 acc[4] = {};
        #pragma unroll
        for (int k0 = 0; k0 < DIN; k0 += 32) {
            const int kk = k0 + ko16;
            bf16x8 b = w8f(W_enc, n * DIN + kk);
            #pragma unroll
            for (int rt = 0; rt < 4; rt++) {
                bf16x8 a = *(const bf16x8*)&T1[oadr(rt * 16 + lc, kk)];
                acc[rt] = mfma16(a, b, acc[rt]);
            }
        }
        #pragma unroll
        for (int rt = 0; rt < 4; rt++)
            #pragma unroll
            for (int i = 0; i < 4; i++) {
                const int row = rt * 16 + quad * 4 + i;
                T0[tadr(row, n)] = f2bf(fmaxf(acc[rt][i] + bias, 0.0f));
            }
    }
    __syncthreads();

    // ---- stage 2: H = X1 @ W_obs^T + b_obs -> T1 (obs dead) ----
    {
        const float bias = b_obs[n];
        f32x4 acc[4] = {};
        #pragma unroll 2
        for (int k0 = 0; k0 < H0; k0 += 32) {
            const int kk = k0 + ko16;
            bf16x8 b = w8f(W_obs, n * H0 + kk);
            #pragma unroll
            for (int rt = 0; rt < 4; rt++) {
                bf16x8 a = *(const bf16x8*)&T0[tadr(rt * 16 + lc, kk)];
                acc[rt] = mfma16(a, b, acc[rt]);
            }
        }
        #pragma unroll
        for (int rt = 0; rt < 4; rt++)
            #pragma unroll
            for (int i = 0; i < 4; i++) {
                const int row = rt * 16 + quad * 4 + i;
                T1[tadr(row, n)] = f2bf(acc[rt][i] + bias);
            }
    }
    __syncthreads();

    // ---- GRU with folded comm.  C = (colsum(H) - H)/64, and colsum commutes
    // with @W^T: gi = (colsum(G) - G)/64 + b_ih, G = H@W_ih^T.
    // Pass A: r,z gates (16 accs). r -> T0 (X1 dead, same-lane slots), z -> regs.
    f32x4 zreg[4];
    {
        const float bir = b_ih[n], biz = b_ih[n + 256];
        const float bhr = b_hh[n], bhz = b_hh[n + 256];
        f32x4 gir[4] = {}, giz[4] = {}, ghr[4] = {}, ghz[4] = {};
        #pragma unroll 2
        for (int k0 = 0; k0 < H0; k0 += 32) {
            const int kk = k0 + ko16;
            bf16x8 bir8 = w8f(W_ih, (n      ) * H0 + kk);
            bf16x8 biz8 = w8f(W_ih, (n + 256) * H0 + kk);
            bf16x8 bhr8 = w8f(W_hh, (n      ) * H0 + kk);
            bf16x8 bhz8 = w8f(W_hh, (n + 256) * H0 + kk);
            #pragma unroll
            for (int rt = 0; rt < 4; rt++) {
                bf16x8 aH = *(const bf16x8*)&T1[tadr(rt * 16 + lc, kk)];
                gir[rt] = mfma16(aH, bir8, gir[rt]);
                giz[rt] = mfma16(aH, biz8, giz[rt]);
                ghr[rt] = mfma16(aH, bhr8, ghr[rt]);
                ghz[rt] = mfma16(aH, bhz8, ghz[rt]);
            }
        }
        float Sr = 0.0f, Sz = 0.0f;
        #pragma unroll
        for (int rt = 0; rt < 4; rt++)
            #pragma unroll
            for (int i = 0; i < 4; i++) { Sr += gir[rt][i]; Sz += giz[rt][i]; }
        Sr += __shfl_xor(Sr, 16); Sr += __shfl_xor(Sr, 32);
        Sz += __shfl_xor(Sz, 16); Sz += __shfl_xor(Sz, 32);
        #pragma unroll
        for (int rt = 0; rt < 4; rt++)
            #pragma unroll
            for (int i = 0; i < 4; i++) {
                const int row = rt * 16 + quad * 4 + i;
                const float gi_r = (Sr - gir[rt][i]) * (1.0f / 64.0f) + bir;
                const float gi_z = (Sz - giz[rt][i]) * (1.0f / 64.0f) + biz;
                T0[tadr(row, n)] = f2bf(fsigmoid(gi_r + ghr[rt][i] + bhr));
                zreg[rt][i]      = fsigmoid(gi_z + ghz[rt][i] + bhz);
            }
    }
    // Pass B: n gate + h' (8 accs). Reads own r slots from T0; h' -> T0.
    {
        const float bin = b_ih[n + 512], bhn = b_hh[n + 512];
        f32x4 gin[4] = {}, ghn[4] = {};
        #pragma unroll 2
        for (int k0 = 0; k0 < H0; k0 += 32) {
            const int kk = k0 + ko16;
            bf16x8 bin8 = w8f(W_ih, (n + 512) * H0 + kk);
            bf16x8 bhn8 = w8f(W_hh, (n + 512) * H0 + kk);
            #pragma unroll
            for (int rt = 0; rt < 4; rt++) {
                bf16x8 aH = *(const bf16x8*)&T1[tadr(rt * 16 + lc, kk)];
                gin[rt] = mfma16(aH, bin8, gin[rt]);
                ghn[rt] = mfma16(aH, bhn8, ghn[rt]);
            }
        }
        float Sn = 0.0f;
        #pragma unroll
        for (int rt = 0; rt < 4; rt++)
            #pragma unroll
            for (int i = 0; i < 4; i++) Sn += gin[rt][i];
        Sn += __shfl_xor(Sn, 16); Sn += __shfl_xor(Sn, 32);
        #pragma unroll
        for (int rt = 0; rt < 4; rt++)
            #pragma unroll
            for (int i = 0; i < 4; i++) {
                const int row = rt * 16 + quad * 4 + i;
                const float gi_n = (Sn - gin[rt][i]) * (1.0f / 64.0f) + bin;
                const float rr = bf2f(T0[tadr(row, n)]);      // own slot
                const float nn = ftanh(gi_n + rr * (ghn[rt][i] + bhn));
                const float z  = zreg[rt][i];
                const float h  = bf2f(T1[tadr(row, n)]);
                T0[tadr(row, n)] = f2bf((1.0f - z) * nn + z * h);
            }
    }
    __syncthreads();

    // ---- value head: V = h' @ W_val^T + b_val -> T1 (H dead) ----
    {
        const float bias = b_val[n];
        f32x4 acc[4] = {};
        #pragma unroll 2
        for (int k0 = 0; k0 < H0; k0 += 32) {
            const int kk = k0 + ko16;
            bf16x8 b = w8f(W_val, n * H0 + kk);
            #pragma unroll
            for (int rt = 0; rt < 4; rt++) {
                bf16x8 a = *(const bf16x8*)&T0[tadr(rt * 16 + lc, kk)];
                acc[rt] = mfma16(a, b, acc[rt]);
            }
        }
        #pragma unroll
        for (int rt = 0; rt < 4; rt++)
            #pragma unroll
            for (int i = 0; i < 4; i++) {
                const int row = rt * 16 + quad * 4 + i;
                T1[tadr(row, n)] = f2bf(acc[rt][i] + bias);
            }
    }
    __syncthreads();

    // ---- decode: OUT = V @ W_dec^T + b_dec -> global fp32 ----
    {
        const int ct = wave & 3;             // 4 col-tiles (H2=64)
        const int rg = wave >> 2;            // 4 row-tiles of 16
        const int nd = ct * 16 + lc;
        const float bias = b_dec[nd];
        f32x4 acc = {};
        #pragma unroll 2
        for (int k0 = 0; k0 < H0; k0 += 32) {
            const int kk = k0 + ko16;
            bf16x8 b = w8f(W_dec, nd * H0 + kk);
            bf16x8 a = *(const bf16x8*)&T1[tadr(rg * 16 + lc, kk)];
            acc = mfma16(a, b, acc);
        }
        #pragma unroll
        for (int i = 0; i < 4; i++) {
            const int row = rg * 16 + quad * 4 + i;
            out[(row0 + row) * 64 + nd] = acc[i] + bias;
        }
    }
}

extern "C" void kernel_launch(void* const* d_in, const int* in_sizes, int n_in,
                              void* d_out, int out_size, void* d_ws, size_t ws_size,
                              hipStream_t stream) {
    (void)in_sizes; (void)n_in; (void)out_size; (void)d_ws; (void)ws_size;
    commnet_mfma<<<256, 1024, 0, stream>>>(
        (const float*)d_in[0],
        (const float*)d_in[1],  (const float*)d_in[2],
        (const float*)d_in[3],  (const float*)d_in[4],
        (const float*)d_in[5],  (const float*)d_in[6],
        (const float*)d_in[7],  (const float*)d_in[8],
        (const float*)d_in[9],  (const float*)d_in[10],
        (const float*)d_in[11], (const float*)d_in[12],
        (float*)d_out);
}

// Round 10
// 122.628 us; speedup vs baseline: 1.4006x; 1.4006x over previous
//
#include <hip/hip_runtime.h>
#include <hip/hip_bf16.h>
#include <math.h>

// CommNetWork fused MFMA kernel v4, MI355X gfx950. fp32 in / fp32 out.
// R9 post-mortem: ~75us total-vs-dispatch gap is constant harness overhead
// (single-kernel run had the same gap); 1024-thr block made the compiler cap
// VGPRs at 64 -> spill. v4 returns to the proven R8 skeleton (prep + 512 thr
// + 2-col passes + folded-comm GRU, VGPR 128 no-spill) and attacks the VALU
// term (30% busy ~= 15.7us): XOR swizzle -> +8 padded stride (affine LDS
// addresses; k-offsets fold into ds_read immediates; bank-exact for b128),
// and libm tanh/exp -> v_exp_f32-based (R9-validated numerics).

typedef __bf16  bf16x8 __attribute__((ext_vector_type(8)));
typedef float   f32x4  __attribute__((ext_vector_type(4)));

#define DIN 128
#define H0  256
#define SW  264   // padded stride, 256-wide tiles: 132 dwords = 4 mod 32 banks
#define SWO 136   // padded stride, 128-wide obs tile
#define LOG2E 1.44269504088896f

// ws element offsets (bf16) for converted weight matrices
#define O_WENC 0
#define O_WOBS 32768
#define O_WIH  98304
#define O_WHH  294912
#define O_WVAL 491520
#define O_WDEC 557056
#define W_TOT  573440   // elements; ws bytes needed = 1146880

__device__ __forceinline__ f32x4 mfma16(bf16x8 a, bf16x8 b, f32x4 c) {
    return __builtin_amdgcn_mfma_f32_16x16x32_bf16(a, b, c, 0, 0, 0);
}
__device__ __forceinline__ float bf2f(__hip_bfloat16 x) { return __bfloat162float(x); }
__device__ __forceinline__ __hip_bfloat16 f2bf(float x) { return __float2bfloat16(x); }

__device__ __forceinline__ float fsigmoid(float x) {
    float e = __builtin_amdgcn_exp2f(-LOG2E * x);
    return __builtin_amdgcn_rcpf(1.0f + e);
}
__device__ __forceinline__ float ftanh(float x) {
    float e = __builtin_amdgcn_exp2f(2.0f * LOG2E * x);
    return 1.0f - 2.0f * __builtin_amdgcn_rcpf(1.0f + e);
}

__device__ __forceinline__ bf16x8 w8(const __hip_bfloat16* p, int idx) {
    return *(const bf16x8*)(p + idx);
}

// affine tile addressing (padded stride)
__device__ __forceinline__ int tadr(int r, int k) { return r * SW + k; }
__device__ __forceinline__ int oadr(int r, int k) { return r * SWO + k; }

// ---- prep: convert 6 weight matrices fp32 -> bf16 into ws (vectorized) ----
__global__ __launch_bounds__(256) void prep_kernel(
    const float* __restrict__ W_enc, const float* __restrict__ W_obs,
    const float* __restrict__ W_ih,  const float* __restrict__ W_hh,
    const float* __restrict__ W_val, const float* __restrict__ W_dec,
    __hip_bfloat16* __restrict__ ws)
{
    const int i = (blockIdx.x * 256 + threadIdx.x) * 8;
    if (i >= W_TOT) return;
    const float* src; int off;
    if      (i < O_WOBS) { src = W_enc; off = O_WENC; }
    else if (i < O_WIH)  { src = W_obs; off = O_WOBS; }
    else if (i < O_WHH)  { src = W_ih;  off = O_WIH;  }
    else if (i < O_WVAL) { src = W_hh;  off = O_WHH;  }
    else if (i < O_WDEC) { src = W_val; off = O_WVAL; }
    else                 { src = W_dec; off = O_WDEC; }
    const float* f = src + (i - off);
    f32x4 a = *(const f32x4*)f;
    f32x4 b = *(const f32x4*)(f + 4);
    bf16x8 v;
    #pragma unroll
    for (int j = 0; j < 4; j++) { v[j] = (__bf16)a[j]; v[j + 4] = (__bf16)b[j]; }
    *(bf16x8*)(ws + i) = v;
}

__global__ __launch_bounds__(512, 2) void commnet_mfma(
    const __hip_bfloat16* __restrict__ ws,
    const float* __restrict__ b_enc, const float* __restrict__ b_obs,
    const float* __restrict__ b_ih,  const float* __restrict__ b_hh,
    const float* __restrict__ b_val, const float* __restrict__ b_dec,
    const float* __restrict__ obs,   float* __restrict__ out)
{
    __shared__ __align__(16) __hip_bfloat16 T0[64 * SW];  // X1 -> h'
    __shared__ __align__(16) __hip_bfloat16 T1[64 * SW];  // obs -> H -> V

    const __hip_bfloat16* W_enc = ws + O_WENC;
    const __hip_bfloat16* W_obs = ws + O_WOBS;
    const __hip_bfloat16* W_ih  = ws + O_WIH;
    const __hip_bfloat16* W_hh  = ws + O_WHH;
    const __hip_bfloat16* W_val = ws + O_WVAL;
    const __hip_bfloat16* W_dec = ws + O_WDEC;

    const int tid  = threadIdx.x;
    const int wave = tid >> 6;
    const int lane = tid & 63;
    const int quad = lane >> 4;
    const int lc   = lane & 15;          // tile col (n) / A-frag row (m)
    const int row0 = blockIdx.x * 64;    // global row base for this batch
    const int ko16 = quad * 8;           // k offset of this lane's fragment

    // ---- stage obs (fp32 global) -> bf16 padded T1 ----
    for (int i = tid; i < 64 * DIN / 8; i += 512) {
        const int r = i >> 4;
        const int c = (i & 15) << 3;
        const float* src = obs + (row0 + r) * DIN + c;
        f32x4 a = *(const f32x4*)src;
        f32x4 b = *(const f32x4*)(src + 4);
        bf16x8 v;
        #pragma unroll
        for (int j = 0; j < 4; j++) { v[j] = (__bf16)a[j]; v[j + 4] = (__bf16)b[j]; }
        *(bf16x8*)&T1[oadr(r, c)] = v;
    }
    __syncthreads();

    // ---- stage 1: X1 = relu(obs @ W_enc^T + b_enc) -> T0 (2 col passes) ----
    #pragma unroll
    for (int cp = 0; cp < 2; cp++) {
        const int n = (wave + 8 * cp) * 16 + lc;
        const float bias = b_enc[n];
        f32x4 acc[4] = {};
        #pragma unroll
        for (int k0 = 0; k0 < DIN; k0 += 32) {
            const int kk = k0 + ko16;
            bf16x8 b = w8(W_enc, n * DIN + kk);
            #pragma unroll
            for (int rt = 0; rt < 4; rt++) {
                bf16x8 a = *(const bf16x8*)&T1[oadr(rt * 16 + lc, kk)];
                acc[rt] = mfma16(a, b, acc[rt]);
            }
        }
        #pragma unroll
        for (int rt = 0; rt < 4; rt++)
            #pragma unroll
            for (int i = 0; i < 4; i++) {
                const int row = rt * 16 + quad * 4 + i;
                T0[tadr(row, n)] = f2bf(fmaxf(acc[rt][i] + bias, 0.0f));
            }
    }
    __syncthreads();

    // ---- stage 2: H = X1 @ W_obs^T + b_obs -> T1 (obs dead) ----
    #pragma unroll
    for (int cp = 0; cp < 2; cp++) {
        const int n = (wave + 8 * cp) * 16 + lc;
        const float bias = b_obs[n];
        f32x4 acc[4] = {};
        #pragma unroll 2
        for (int k0 = 0; k0 < H0; k0 += 32) {
            const int kk = k0 + ko16;
            bf16x8 b = w8(W_obs, n * H0 + kk);
            #pragma unroll
            for (int rt = 0; rt < 4; rt++) {
                bf16x8 a = *(const bf16x8*)&T0[tadr(rt * 16 + lc, kk)];
                acc[rt] = mfma16(a, b, acc[rt]);
            }
        }
        #pragma unroll
        for (int rt = 0; rt < 4; rt++)
            #pragma unroll
            for (int i = 0; i < 4; i++) {
                const int row = rt * 16 + quad * 4 + i;
                T1[tadr(row, n)] = f2bf(acc[rt][i] + bias);
            }
    }
    __syncthreads();

    // ---- GRU with folded comm (2 col passes, h' -> T0) ----
    // gi = C@W_ih^T + b_ih with C = (colsum(H) - H)/64; colsum commutes with
    // @W^T, so gi = (colsum(G) - G)/64 + b_ih, G = H@W_ih^T. Each wave owns
    // its 16 columns for all 64 rows: colsum = in-lane sum + shfl_xor(16,32).
    #pragma unroll
    for (int cp = 0; cp < 2; cp++) {
        const int n = (wave + 8 * cp) * 16 + lc;
        const float bir = b_ih[n], biz = b_ih[n + 256], bin = b_ih[n + 512];
        const float bhr = b_hh[n], bhz = b_hh[n + 256], bhn = b_hh[n + 512];
        f32x4 gir[4] = {}, giz[4] = {}, gin[4] = {};
        f32x4 ghr[4] = {}, ghz[4] = {}, ghn[4] = {};
        #pragma unroll 2
        for (int k0 = 0; k0 < H0; k0 += 32) {
            const int kk = k0 + ko16;
            bf16x8 bir8 = w8(W_ih, (n      ) * H0 + kk);
            bf16x8 biz8 = w8(W_ih, (n + 256) * H0 + kk);
            bf16x8 bin8 = w8(W_ih, (n + 512) * H0 + kk);
            bf16x8 bhr8 = w8(W_hh, (n      ) * H0 + kk);
            bf16x8 bhz8 = w8(W_hh, (n + 256) * H0 + kk);
            bf16x8 bhn8 = w8(W_hh, (n + 512) * H0 + kk);
            #pragma unroll
            for (int rt = 0; rt < 4; rt++) {
                bf16x8 aH = *(const bf16x8*)&T1[tadr(rt * 16 + lc, kk)];
                gir[rt] = mfma16(aH, bir8, gir[rt]);
                giz[rt] = mfma16(aH, biz8, giz[rt]);
                gin[rt] = mfma16(aH, bin8, gin[rt]);
                ghr[rt] = mfma16(aH, bhr8, ghr[rt]);
                ghz[rt] = mfma16(aH, bhz8, ghz[rt]);
                ghn[rt] = mfma16(aH, bhn8, ghn[rt]);
            }
        }
        float Sr = 0.0f, Sz = 0.0f, Sn = 0.0f;
        #pragma unroll
        for (int rt = 0; rt < 4; rt++)
            #pragma unroll
            for (int i = 0; i < 4; i++) {
                Sr += gir[rt][i]; Sz += giz[rt][i]; Sn += gin[rt][i];
            }
        Sr += __shfl_xor(Sr, 16); Sr += __shfl_xor(Sr, 32);
        Sz += __shfl_xor(Sz, 16); Sz += __shfl_xor(Sz, 32);
        Sn += __shfl_xor(Sn, 16); Sn += __shfl_xor(Sn, 32);

        #pragma unroll
        for (int rt = 0; rt < 4; rt++)
            #pragma unroll
            for (int i = 0; i < 4; i++) {
                const int row = rt * 16 + quad * 4 + i;
                const float gi_r = (Sr - gir[rt][i]) * (1.0f / 64.0f) + bir;
                const float gi_z = (Sz - giz[rt][i]) * (1.0f / 64.0f) + biz;
                const float gi_n = (Sn - gin[rt][i]) * (1.0f / 64.0f) + bin;
                const float r  = fsigmoid(gi_r + ghr[rt][i] + bhr);
                const float z  = fsigmoid(gi_z + ghz[rt][i] + bhz);
                const float nn = ftanh(gi_n + r * (ghn[rt][i] + bhn));
                const float h  = bf2f(T1[tadr(row, n)]);
                T0[tadr(row, n)] = f2bf((1.0f - z) * nn + z * h);
            }
    }
    __syncthreads();

    // ---- value head: V = h' @ W_val^T + b_val -> T1 (H dead) ----
    #pragma unroll
    for (int cp = 0; cp < 2; cp++) {
        const int n = (wave + 8 * cp) * 16 + lc;
        const float bias = b_val[n];
        f32x4 acc[4] = {};
        #pragma unroll 2
        for (int k0 = 0; k0 < H0; k0 += 32) {
            const int kk = k0 + ko16;
            bf16x8 b = w8(W_val, n * H0 + kk);
            #pragma unroll
            for (int rt = 0; rt < 4; rt++) {
                bf16x8 a = *(const bf16x8*)&T0[tadr(rt * 16 + lc, kk)];
                acc[rt] = mfma16(a, b, acc[rt]);
            }
        }
        #pragma unroll
        for (int rt = 0; rt < 4; rt++)
            #pragma unroll
            for (int i = 0; i < 4; i++) {
                const int row = rt * 16 + quad * 4 + i;
                T1[tadr(row, n)] = f2bf(acc[rt][i] + bias);
            }
    }
    __syncthreads();

    // ---- decode: OUT = V @ W_dec^T + b_dec -> global fp32 ----
    {
        const int ct  = wave & 3;          // 4 col-tiles (H2=64)
        const int rtb = (wave >> 2) * 2;   // waves 0-3: rows 0..31, 4-7: 32..63
        const int n   = ct * 16 + lc;
        const float bias = b_dec[n];
        f32x4 acc[2] = {};
        #pragma unroll 2
        for (int k0 = 0; k0 < H0; k0 += 32) {
            const int kk = k0 + ko16;
            bf16x8 b = w8(W_dec, n * H0 + kk);
            #pragma unroll
            for (int j = 0; j < 2; j++) {
                bf16x8 a = *(const bf16x8*)&T1[tadr((rtb + j) * 16 + lc, kk)];
                acc[j] = mfma16(a, b, acc[j]);
            }
        }
        #pragma unroll
        for (int j = 0; j < 2; j++)
            #pragma unroll
            for (int i = 0; i < 4; i++) {
                const int row = (rtb + j) * 16 + quad * 4 + i;
                out[(row0 + row) * 64 + n] = acc[j][i] + bias;
            }
    }
}

extern "C" void kernel_launch(void* const* d_in, const int* in_sizes, int n_in,
                              void* d_out, int out_size, void* d_ws, size_t ws_size,
                              hipStream_t stream) {
    (void)in_sizes; (void)n_in; (void)out_size; (void)ws_size;
    const float* obs   = (const float*)d_in[0];
    const float* W_enc = (const float*)d_in[1];  const float* b_enc = (const float*)d_in[2];
    const float* W_obs = (const float*)d_in[3];  const float* b_obs = (const float*)d_in[4];
    const float* W_ih  = (const float*)d_in[5];  const float* b_ih  = (const float*)d_in[6];
    const float* W_hh  = (const float*)d_in[7];  const float* b_hh  = (const float*)d_in[8];
    const float* W_val = (const float*)d_in[9];  const float* b_val = (const float*)d_in[10];
    const float* W_dec = (const float*)d_in[11]; const float* b_dec = (const float*)d_in[12];
    float* out = (float*)d_out;
    __hip_bfloat16* ws = (__hip_bfloat16*)d_ws;

    prep_kernel<<<280, 256, 0, stream>>>(W_enc, W_obs, W_ih, W_hh, W_val, W_dec, ws);
    commnet_mfma<<<256, 512, 0, stream>>>(
        ws, b_enc, b_obs, b_ih, b_hh, b_val, b_dec, obs, out);
}